// Round 10
// baseline (554.182 us; speedup 1.0000x reference)
//
#include <hip/hip_runtime.h>
#include <stdint.h>

// Problem dims (fixed by reference)
#define B_ 4
#define S_ 2048
#define D_ 1024
#define H_ 16
#define DFF_ 4096
#define QSTR 3072  // fused QKV output width

typedef __attribute__((ext_vector_type(8))) short short8;
typedef __attribute__((ext_vector_type(4))) short short4v;
typedef __attribute__((ext_vector_type(4))) float floatx4;
typedef __attribute__((ext_vector_type(16))) float floatx16;

typedef const __attribute__((address_space(1))) void* gas_ptr;
typedef __attribute__((address_space(3))) void* las_ptr;

__device__ __forceinline__ short f2bf(float f) {
  union { float f; uint32_t u; } v; v.f = f;
  uint32_t r = v.u + 0x7fffu + ((v.u >> 16) & 1u);
  return (short)(r >> 16);
}

// ---------------------------------------------------------------------------
// LayerNorm: fp32 row in -> bf16 row out.  One block per row, 256 threads.
// ---------------------------------------------------------------------------
__global__ __launch_bounds__(256) void ln_kernel(
    const float* __restrict__ x, const float* __restrict__ g,
    const float* __restrict__ be, short* __restrict__ out)
{
  const int row = blockIdx.x;
  const int tid = threadIdx.x;
  const float4 v = ((const float4*)(x + (size_t)row * D_))[tid];
  float s1 = v.x + v.y + v.z + v.w;
  float s2 = v.x*v.x + v.y*v.y + v.z*v.z + v.w*v.w;
#pragma unroll
  for (int off = 1; off < 64; off <<= 1) {
    s1 += __shfl_xor(s1, off);
    s2 += __shfl_xor(s2, off);
  }
  __shared__ float r1[4], r2[4];
  if ((tid & 63) == 0) { r1[tid >> 6] = s1; r2[tid >> 6] = s2; }
  __syncthreads();
  s1 = r1[0] + r1[1] + r1[2] + r1[3];
  s2 = r2[0] + r2[1] + r2[2] + r2[3];
  const float mu = s1 * (1.0f / D_);
  const float var = s2 * (1.0f / D_) - mu * mu;
  const float rs = rsqrtf(var + 1e-5f);
  const float4 gv = ((const float4*)g)[tid];
  const float4 bv = ((const float4*)be)[tid];
  short4v o;
  o.x = f2bf((v.x - mu) * rs * gv.x + bv.x);
  o.y = f2bf((v.y - mu) * rs * gv.y + bv.y);
  o.z = f2bf((v.z - mu) * rs * gv.z + bv.z);
  o.w = f2bf((v.w - mu) * rs * gv.w + bv.w);
  *(short4v*)&out[(size_t)row * D_ + tid * 4] = o;
}

// ---------------------------------------------------------------------------
// Batched weight transpose + cast: all six weights in ONE launch.
// ---------------------------------------------------------------------------
__global__ __launch_bounds__(256) void transpose_all(
    const float* __restrict__ wq, const float* __restrict__ wk,
    const float* __restrict__ wv, const float* __restrict__ wo,
    const float* __restrict__ w1, const float* __restrict__ w2,
    short* __restrict__ wqkvT, short* __restrict__ woT,
    short* __restrict__ w1T, short* __restrict__ w2T)
{
  const uint32_t pid = blockIdx.x;
  const float* in; short* out;
  int R, C, tile, xsh;
  if (pid < 4096) {
    const int which = pid >> 10; tile = pid & 1023;
    R = 1024; C = 1024; xsh = 5;
    in  = (which == 0) ? wq : (which == 1) ? wk : (which == 2) ? wv : wo;
    out = (which == 3) ? woT : wqkvT + (size_t)which * 1024 * 1024;
  } else if (pid < 8192) {
    tile = pid - 4096; R = 1024; C = 4096; xsh = 7; in = w1; out = w1T;
  } else {
    tile = pid - 8192; R = 4096; C = 1024; xsh = 5; in = w2; out = w2T;
  }
  const int c0 = (tile & ((1 << xsh) - 1)) * 32;
  const int r0 = (tile >> xsh) * 32;

  __shared__ float t[32][33];
  const int tx = threadIdx.x & 31, ty = threadIdx.x >> 5;
#pragma unroll
  for (int i = 0; i < 4; i++)
    t[ty + i * 8][tx] = in[(size_t)(r0 + ty + i * 8) * C + c0 + tx];
  __syncthreads();
#pragma unroll
  for (int i = 0; i < 4; i++)
    out[(size_t)(c0 + ty + i * 8) * R + r0 + tx] = f2bf(t[tx][ty + i * 8]);
}

// ---------------------------------------------------------------------------
// bf16 GEMM (128x128): C[M,N] = A[M,K] @ Bt[N,K]^T.
// R17/R14 shape (measured best, conflicts 0): 64-k step, stage-8-DMA +
// vmcnt(0)-drain barrier, granule XOR-swizzle.
//   LDS[R][g] = SRC[R][g ^ swz(R)], swz(R) = (R>>1)&3
//   staging source granule = (lane&3)^((lane>>3)&3); read = quad^((l16>>1)&3)
// ---------------------------------------------------------------------------
__global__ __launch_bounds__(256, 4) void gemm_bt(
    const short* __restrict__ A, const short* __restrict__ Bt,
    float* __restrict__ outf, short* __restrict__ outb,
    short* __restrict__ outbK, short* __restrict__ vtT,
    const float* __restrict__ bias, const float* __restrict__ resid,
    int M, int N, int K, int do_relu, int split, int group)
{
  __shared__ short As[2 * 128 * 32];   // [half][row][32]
  __shared__ short Bs[2 * 128 * 32];
  const int tid = threadIdx.x;
  const int wave = tid >> 6;
  const int lane = tid & 63;
  const int quad = lane >> 4;
  const int l16 = lane & 15;

  const uint32_t nblk = gridDim.x;
  const uint32_t pid = blockIdx.y * nblk + blockIdx.x;
  const uint32_t nig = (uint32_t)group * nblk;
  const uint32_t gid = pid / nig;
  const uint32_t within = pid - gid * nig;
  const uint32_t bm = gid * group + within % group;
  const uint32_t bn = within / group;
  const int tm = bm * 128;
  const int tn = bn * 128;

  const int wm = (wave & 1) * 64;
  const int wn = (wave >> 1) * 64;
  const int srow = lane >> 2;
  const int sgran = ((lane & 3) ^ ((lane >> 3) & 3)) * 8;  // swizzled source granule
  const int rg = (l16 >> 1) & 3;                           // read-side swizzle

  floatx4 acc[4][4];
#pragma unroll
  for (int i = 0; i < 4; i++)
#pragma unroll
    for (int j = 0; j < 4; j++) acc[i][j] = floatx4{0.f, 0.f, 0.f, 0.f};

  const short* gA0 = A + (size_t)(tm + wave * 32 + srow) * K + sgran;
  const short* gB0 = Bt + (size_t)(tn + wave * 32 + srow) * K + sgran;

  for (int kt = 0; kt < K; kt += 64) {
    __syncthreads();
    __builtin_amdgcn_global_load_lds((gas_ptr)(gA0 + kt),                      (las_ptr)(&As[wave * 1024]),        16, 0, 0);
    __builtin_amdgcn_global_load_lds((gas_ptr)(gA0 + kt + (size_t)16 * K),     (las_ptr)(&As[wave * 1024 + 512]),  16, 0, 0);
    __builtin_amdgcn_global_load_lds((gas_ptr)(gB0 + kt),                      (las_ptr)(&Bs[wave * 1024]),        16, 0, 0);
    __builtin_amdgcn_global_load_lds((gas_ptr)(gB0 + kt + (size_t)16 * K),     (las_ptr)(&Bs[wave * 1024 + 512]),  16, 0, 0);
    __builtin_amdgcn_global_load_lds((gas_ptr)(gA0 + kt + 32),                 (las_ptr)(&As[4096 + wave * 1024]),       16, 0, 0);
    __builtin_amdgcn_global_load_lds((gas_ptr)(gA0 + kt + 32 + (size_t)16 * K),(las_ptr)(&As[4096 + wave * 1024 + 512]), 16, 0, 0);
    __builtin_amdgcn_global_load_lds((gas_ptr)(gB0 + kt + 32),                 (las_ptr)(&Bs[4096 + wave * 1024]),       16, 0, 0);
    __builtin_amdgcn_global_load_lds((gas_ptr)(gB0 + kt + 32 + (size_t)16 * K),(las_ptr)(&Bs[4096 + wave * 1024 + 512]), 16, 0, 0);
    __syncthreads();

#pragma unroll
    for (int ksub = 0; ksub < 2; ksub++) {
      const int hb = ksub * 4096;
      short8 af[4], bfv[4];
#pragma unroll
      for (int mi = 0; mi < 4; mi++)
        af[mi] = *(const short8*)&As[hb + (wm + mi * 16 + l16) * 32 + (quad ^ rg) * 8];
#pragma unroll
      for (int ni = 0; ni < 4; ni++)
        bfv[ni] = *(const short8*)&Bs[hb + (wn + ni * 16 + l16) * 32 + (quad ^ rg) * 8];
#pragma unroll
      for (int mi = 0; mi < 4; mi++)
#pragma unroll
        for (int ni = 0; ni < 4; ni++)
          acc[mi][ni] = __builtin_amdgcn_mfma_f32_16x16x32_bf16(af[mi], bfv[ni], acc[mi][ni], 0, 0, 0);
    }
  }

  short* ob = outb;
  int Nst = N;
  int cbase = tn;
  int vpart = 0;
  if (split) {
    const int part = tn >> 10;
    if (part == 2) vpart = 1;
    else ob = (part == 0) ? outb : outbK;
    Nst = D_;
    cbase = tn & (D_ - 1);
  }

  if (vpart) {
#pragma unroll
    for (int mi = 0; mi < 4; mi++) {
      const int row0 = tm + wm + mi * 16 + quad * 4;
      const int bb = row0 >> 11, s0r = row0 & 2047;
#pragma unroll
      for (int ni = 0; ni < 4; ni++) {
        const int cst = cbase + wn + ni * 16 + l16;
        short4v o;
#pragma unroll
        for (int r = 0; r < 4; r++) o[r] = f2bf(acc[mi][ni][r]);
        *(short4v*)&vtT[((size_t)(bb << 10) + cst) * (size_t)S_ + s0r] = o;
      }
    }
    return;
  }

#pragma unroll
  for (int mi = 0; mi < 4; mi++) {
    const int row0 = tm + wm + mi * 16 + quad * 4;
#pragma unroll
    for (int ni = 0; ni < 4; ni++) {
      const int col = tn + wn + ni * 16 + l16;
      const int cst = cbase + wn + ni * 16 + l16;
      const float bv = bias ? bias[col] : 0.0f;
#pragma unroll
      for (int r = 0; r < 4; r++) {
        const size_t idx = (size_t)(row0 + r) * Nst + cst;
        float v = acc[mi][ni][r] + bv;
        if (do_relu) v = fmaxf(v, 0.0f);
        if (resid) v += resid[idx];
        if (outf) outf[idx] = v;
        if (ob) ob[idx] = f2bf(v);
      }
    }
  }
}

// ---------------------------------------------------------------------------
// bf16 GEMM (128x64), R18: BK=128 (was 64).  The kernel is latency-bound on
// the per-step barrier drain (measured: 64 steps x ~1.6us, compute ~0.4us,
// conflicts 0, no pipe >30%).  BK=128 halves drain events (64->32 steps),
// doubles per-step compute and DMAs-in-flight (6->12, better MLP).
// LDS 48 KB (4 ksub bufs: A 4x8KB + B 4x4KB) -> 3 blocks/CU (not the m132
// 64KB/2-block trap).  Swizzle formulas invariant (staging base rows == 0
// mod 16 -> swz = (lane>>3)&3; read rows -> (l16>>1)&3).  Conflicts stay 0.
// ---------------------------------------------------------------------------
__global__ __launch_bounds__(256, 3) void gemm_bt_n64(
    const short* __restrict__ A, const short* __restrict__ Bt,
    float* __restrict__ outf,
    const float* __restrict__ bias, const float* __restrict__ resid,
    int M, int N, int K, int group)
{
  __shared__ short As[4][128 * 32];   // [ksub][row][32 shorts]  32 KB
  __shared__ short Bs[4][64 * 32];    // [ksub][row][32 shorts]  16 KB
  const int tid = threadIdx.x;
  const int wave = tid >> 6;
  const int lane = tid & 63;
  const int quad = lane >> 4;
  const int l16 = lane & 15;

  const uint32_t nblk = gridDim.x;
  const uint32_t pid = blockIdx.y * nblk + blockIdx.x;
  const uint32_t nig = (uint32_t)group * nblk;
  const uint32_t gid = pid / nig;
  const uint32_t within = pid - gid * nig;
  const uint32_t bm = gid * group + within % group;
  const uint32_t bn = within / group;
  const int tm = bm * 128;
  const int tn = bn * 64;

  const int wm = (wave & 1) * 64;
  const int wn = (wave >> 1) * 32;
  const int srow = lane >> 2;
  const int sgran = ((lane & 3) ^ ((lane >> 3) & 3)) * 8;  // swizzled source granule
  const int rg = (l16 >> 1) & 3;                           // read-side swizzle

  floatx4 acc[4][2];
#pragma unroll
  for (int i = 0; i < 4; i++)
#pragma unroll
    for (int j = 0; j < 2; j++) acc[i][j] = floatx4{0.f, 0.f, 0.f, 0.f};

  const short* gA0 = A + (size_t)(tm + wave * 32 + srow) * K + sgran;
  const short* gB0 = Bt + (size_t)(tn + wave * 16 + srow) * K + sgran;

  for (int kt = 0; kt < K; kt += 128) {
    __syncthreads();
    // A: 4 ksubs x 2 row-halves = 8 issues/wave
#pragma unroll
    for (int ks = 0; ks < 4; ks++) {
      __builtin_amdgcn_global_load_lds((gas_ptr)(gA0 + kt + ks * 32),                  (las_ptr)(&As[ks][wave * 1024]),        16, 0, 0);
      __builtin_amdgcn_global_load_lds((gas_ptr)(gA0 + kt + ks * 32 + (size_t)16 * K), (las_ptr)(&As[ks][wave * 1024 + 512]),  16, 0, 0);
      __builtin_amdgcn_global_load_lds((gas_ptr)(gB0 + kt + ks * 32),                  (las_ptr)(&Bs[ks][wave * 512]),         16, 0, 0);
    }
    __syncthreads();

#pragma unroll
    for (int ks = 0; ks < 4; ks++) {
      short8 af[4], bfv[2];
#pragma unroll
      for (int mi = 0; mi < 4; mi++)
        af[mi] = *(const short8*)&As[ks][(wm + mi * 16 + l16) * 32 + (quad ^ rg) * 8];
#pragma unroll
      for (int ni = 0; ni < 2; ni++)
        bfv[ni] = *(const short8*)&Bs[ks][(wn + ni * 16 + l16) * 32 + (quad ^ rg) * 8];
#pragma unroll
      for (int mi = 0; mi < 4; mi++)
#pragma unroll
        for (int ni = 0; ni < 2; ni++)
          acc[mi][ni] = __builtin_amdgcn_mfma_f32_16x16x32_bf16(af[mi], bfv[ni], acc[mi][ni], 0, 0, 0);
    }
  }

#pragma unroll
  for (int mi = 0; mi < 4; mi++) {
    const int row0 = tm + wm + mi * 16 + quad * 4;
#pragma unroll
    for (int ni = 0; ni < 2; ni++) {
      const int col = tn + wn + ni * 16 + l16;
      const float bv = bias ? bias[col] : 0.0f;
#pragma unroll
      for (int r = 0; r < 4; r++) {
        const size_t idx = (size_t)(row0 + r) * N + col;
        float v = acc[mi][ni][r] + bv;
        if (resid) v += resid[idx];
        outf[idx] = v;
      }
    }
  }
}

// ---------------------------------------------------------------------------
// Flash attention, R13 (proven in R3): in-register softmax (swapped QK^T,
// 32x32x16 MFMA, cvt_pk + permlane32_swap); K/V staged via global_load_lds
// double-buffer, DMA issued post-barrier (full compute phase of overlap);
// source-permuted granule swizzle; s_setprio around MFMA clusters.
// ---------------------------------------------------------------------------
__device__ __forceinline__ int swz64(int row) {
  return (row & 7) ^ ((row >> 3) & 3);
}
__device__ __forceinline__ int kvidx(int row, int scol) {
  // scol in shorts (multiple of 8); granule XOR-swizzled by swz64(row)
  return (row << 6) + (scol ^ (swz64(row) << 3));
}

__global__ __launch_bounds__(256, 4) void attn_kernel(
    const short* __restrict__ qb, const short* __restrict__ kb,
    const short* __restrict__ vtb, short* __restrict__ attb)
{
  __shared__ short Ks[2][64 * 64];
  __shared__ short Vts[2][64 * 64];
  __shared__ float lbuf[4][32];

  const int tid = threadIdx.x;
  const int wave = tid >> 6, lane = tid & 63;
  const int l31 = lane & 31, hi = lane >> 5;
  const int qt = blockIdx.x, bh = blockIdx.y;   // qt: 0..15 (128 q each)
  const int b = bh >> 4, h = bh & 15;
  const size_t rowbase = (size_t)b * S_;
  const int hcol = h * 64;

  // staging geometry (global_load_lds: wave-uniform LDS base + lane*16B)
  const int lr = lane >> 3, lg = lane & 7;
  const int sgran = (lg ^ lr ^ wave) * 8;  // source column offset in shorts
  const short* ksrc = kb + (rowbase + wave * 8 + lr) * D_ + hcol + sgran;
  const short* vsrc = vtb + ((size_t)bh * 64 + wave * 8 + lr) * S_ + sgran;

  // Q fragments (B-operand: row=q=l31 within wave's 32, elems d=st*16+hi*8+i),
  // prescaled by log2(e)/8.
  short8 qf[4];
  {
    const short* gq = qb + (rowbase + qt * 128 + wave * 32 + l31) * D_ + hcol + hi * 8;
#pragma unroll
    for (int st = 0; st < 4; st++) {
      short8 t = *(const short8*)(gq + st * 16);
#pragma unroll
      for (int i = 0; i < 8; i++) {
        const float f = __uint_as_float(((uint32_t)(uint16_t)t[i]) << 16) * 0.18033688f;
        t[i] = (short)((__float_as_uint(f) + 0x8000u) >> 16);
      }
      qf[st] = t;
    }
  }

  floatx16 Of[2];
#pragma unroll
  for (int nd = 0; nd < 2; nd++)
#pragma unroll
    for (int i = 0; i < 16; i++) Of[nd][i] = 0.f;
  float lrun0 = 0.f, lrun1 = 0.f;

  // prologue: stage tile 0 into buf 0 (4 DMA issues per wave)
  __builtin_amdgcn_global_load_lds((gas_ptr)ksrc,                      (las_ptr)(&Ks[0][(wave * 8) * 64]),        16, 0, 0);
  __builtin_amdgcn_global_load_lds((gas_ptr)(ksrc + (size_t)32 * D_),  (las_ptr)(&Ks[0][(32 + wave * 8) * 64]),   16, 0, 0);
  __builtin_amdgcn_global_load_lds((gas_ptr)vsrc,                      (las_ptr)(&Vts[0][(wave * 8) * 64]),       16, 0, 0);
  __builtin_amdgcn_global_load_lds((gas_ptr)(vsrc + (size_t)32 * S_),  (las_ptr)(&Vts[0][(32 + wave * 8) * 64]),  16, 0, 0);

  for (int kt = 0; kt < S_; kt += 64) {
    const int cur = (kt >> 6) & 1;
    __syncthreads();  // drains buf[cur] DMA (issued last iter, overlapped)

    if (kt + 64 < S_) {  // issue next-tile DMA; lands during compute below
      const int nxt = cur ^ 1;
      const short* kp = ksrc + (size_t)(kt + 64) * D_;
      const short* vp = vsrc + (kt + 64);
      __builtin_amdgcn_global_load_lds((gas_ptr)kp,                      (las_ptr)(&Ks[nxt][(wave * 8) * 64]),        16, 0, 0);
      __builtin_amdgcn_global_load_lds((gas_ptr)(kp + (size_t)32 * D_),  (las_ptr)(&Ks[nxt][(32 + wave * 8) * 64]),   16, 0, 0);
      __builtin_amdgcn_global_load_lds((gas_ptr)vp,                      (las_ptr)(&Vts[nxt][(wave * 8) * 64]),       16, 0, 0);
      __builtin_amdgcn_global_load_lds((gas_ptr)(vp + (size_t)32 * S_),  (las_ptr)(&Vts[nxt][(32 + wave * 8) * 64]),  16, 0, 0);
    }

#pragma unroll
    for (int sub = 0; sub < 2; sub++) {
      // S^T[k, q] over 32 k-rows, K-dim = d (4 chained MFMAs)
      floatx16 s;
#pragma unroll
      for (int i = 0; i < 16; i++) s[i] = 0.f;
      __builtin_amdgcn_s_setprio(1);
#pragma unroll
      for (int st = 0; st < 4; st++) {
        const short8 kf = *(const short8*)&Ks[cur][kvidx(sub * 32 + l31, st * 16 + hi * 8)];
        s = __builtin_amdgcn_mfma_f32_32x32x16_bf16(kf, qf[st], s, 0, 0, 0);
      }
      __builtin_amdgcn_s_setprio(0);
      // softmax numerator, in-register (lane-local: one q per lane)
      float p[16];
#pragma unroll
      for (int i = 0; i < 16; i++) {
        p[i] = __builtin_amdgcn_exp2f(s[i]);
        if (i & 1) lrun1 += p[i]; else lrun0 += p[i];
      }
      // pack P into PV A-frags: per 16-k window 4 cvt_pk + 2 permlane32_swap
      short8 pf[2];
#pragma unroll
      for (int kw = 0; kw < 2; kw++) {
        const int o = kw * 8;
        uint32_t wa, wb, wc, wd;
        asm("v_cvt_pk_bf16_f32 %0, %1, %2" : "=v"(wa) : "v"(p[o + 0]), "v"(p[o + 1]));
        asm("v_cvt_pk_bf16_f32 %0, %1, %2" : "=v"(wb) : "v"(p[o + 4]), "v"(p[o + 5]));
        asm("v_cvt_pk_bf16_f32 %0, %1, %2" : "=v"(wc) : "v"(p[o + 2]), "v"(p[o + 3]));
        asm("v_cvt_pk_bf16_f32 %0, %1, %2" : "=v"(wd) : "v"(p[o + 6]), "v"(p[o + 7]));
        asm("v_permlane32_swap_b32 %0, %1" : "+v"(wa), "+v"(wb));
        asm("v_permlane32_swap_b32 %0, %1" : "+v"(wc), "+v"(wd));
        union { uint32_t u[4]; short8 s8; } pk;
        pk.u[0] = wa; pk.u[1] = wc; pk.u[2] = wb; pk.u[3] = wd;
        pf[kw] = pk.s8;
      }
      // PV: O[q, d] += P[q, k-window] * Vt[d, k-window]
      __builtin_amdgcn_s_setprio(1);
#pragma unroll
      for (int kw = 0; kw < 2; kw++)
#pragma unroll
        for (int nd = 0; nd < 2; nd++) {
          const short8 vf = *(const short8*)&Vts[cur][kvidx(nd * 32 + l31, sub * 32 + kw * 16 + hi * 8)];
          Of[nd] = __builtin_amdgcn_mfma_f32_32x32x16_bf16(pf[kw], vf, Of[nd], 0, 0, 0);
        }
      __builtin_amdgcn_s_setprio(0);
    }
  }

  // l: lane's partial covers half the k per q; partner lane (hi^1) has the rest
  const float lrun = lrun0 + lrun1;
  const float ltot = lrun + __shfl_xor(lrun, 32);
  if (hi == 0) lbuf[wave][l31] = ltot;
  asm volatile("" ::: "memory");  // wave-private LDS; compiler orders via lgkmcnt
#pragma unroll
  for (int reg = 0; reg < 16; reg++) {
    const int q = (reg & 3) + 4 * hi + 8 * (reg >> 2);
    const float inv = 1.0f / lbuf[wave][q];
    const size_t base = (rowbase + qt * 128 + wave * 32 + q) * D_ + hcol + l31;
    attb[base]      = f2bf(Of[0][reg] * inv);
    attb[base + 32] = f2bf(Of[1][reg] * inv);
  }
}

// ---------------------------------------------------------------------------
extern "C" void kernel_launch(void* const* d_in, const int* in_sizes, int n_in,
                              void* d_out, int out_size, void* d_ws, size_t ws_size,
                              hipStream_t stream) {
  const float* x   = (const float*)d_in[0];
  const float* wq  = (const float*)d_in[1];
  const float* wk  = (const float*)d_in[2];
  const float* wv  = (const float*)d_in[3];
  const float* wo  = (const float*)d_in[4];
  const float* w1  = (const float*)d_in[5];
  const float* b1  = (const float*)d_in[6];
  const float* w2  = (const float*)d_in[7];
  const float* b2  = (const float*)d_in[8];
  const float* g1  = (const float*)d_in[9];
  const float* be1 = (const float*)d_in[10];
  const float* g2  = (const float*)d_in[11];
  const float* be2 = (const float*)d_in[12];
  float* out = (float*)d_out;

  const size_t MROWS = (size_t)B_ * S_;  // 8192
  char* p = (char*)d_ws;
  auto take = [&](size_t bytes) { char* r = p; p += (bytes + 255) & ~(size_t)255; return r; };
  short* hb    = (short*)take(MROWS * D_ * 2);   // LN1 out
  short* h2b   = (short*)take(MROWS * D_ * 2);
  short* qbuf  = (short*)take(MROWS * D_ * 2);
  short* kbuf  = (short*)take(MROWS * D_ * 2);
  short* vtb   = (short*)take(MROWS * D_ * 2);   // V transposed (written by QKV GEMM)
  short* attb  = (short*)take(MROWS * D_ * 2);
  short* ffb   = (short*)take(MROWS * DFF_ * 2);
  short* wqkvT = (short*)take((size_t)3 * D_ * D_ * 2);
  short* woT   = (short*)take((size_t)D_ * D_ * 2);
  short* w1T   = (short*)take((size_t)D_ * DFF_ * 2);
  short* w2T   = (short*)take((size_t)DFF_ * D_ * 2);
  float* x1    = (float*)take(MROWS * D_ * 4);

  transpose_all<<<12288, 256, 0, stream>>>(wq, wk, wv, wo, w1, w2,
                                           wqkvT, woT, w1T, w2T);

  ln_kernel<<<MROWS, 256, 0, stream>>>(x, g1, be1, hb);

  gemm_bt<<<dim3(QSTR / 128, MROWS / 128), 256, 0, stream>>>(
      hb, wqkvT, nullptr, qbuf, kbuf, vtb, nullptr, nullptr, MROWS, QSTR, D_, 0, 1, 8);

  attn_kernel<<<dim3(S_ / 128, B_ * H_), 256, 0, stream>>>(qbuf, kbuf, vtb, attb);

  // AO: 128x128 tiles (R14 config, conflicts 0, latency-tolerant at K=1024)
  gemm_bt<<<dim3(D_ / 128, MROWS / 128), 256, 0, stream>>>(
      attb, woT, x1, nullptr, nullptr, nullptr, nullptr, x, MROWS, D_, D_, 0, 0, 8);

  ln_kernel<<<MROWS, 256, 0, stream>>>(x1, g2, be2, h2b);

  gemm_bt<<<dim3(DFF_ / 128, MROWS / 128), 256, 0, stream>>>(
      h2b, w1T, nullptr, ffb, nullptr, nullptr, b1, nullptr, MROWS, DFF_, D_, 1, 0, 8);

  // FFN2: n64 BK=128 (3 blocks/CU, 32 K-steps, 12 DMAs in flight)
  gemm_bt_n64<<<dim3(D_ / 64, MROWS / 128), 256, 0, stream>>>(
      ffb, w2T, out, b2, x1, MROWS, D_, DFF_, 4);

  (void)in_sizes; (void)n_in; (void)out_size; (void)ws_size;
}

// Round 11
// 525.812 us; speedup vs baseline: 1.0540x; 1.0540x over previous
//
#include <hip/hip_runtime.h>
#include <stdint.h>

// Problem dims (fixed by reference)
#define B_ 4
#define S_ 2048
#define D_ 1024
#define H_ 16
#define DFF_ 4096
#define QSTR 3072  // fused QKV output width

typedef __attribute__((ext_vector_type(8))) short short8;
typedef __attribute__((ext_vector_type(4))) short short4v;
typedef __attribute__((ext_vector_type(4))) float floatx4;
typedef __attribute__((ext_vector_type(16))) float floatx16;

typedef const __attribute__((address_space(1))) void* gas_ptr;
typedef __attribute__((address_space(3))) void* las_ptr;

__device__ __forceinline__ short f2bf(float f) {
  union { float f; uint32_t u; } v; v.f = f;
  uint32_t r = v.u + 0x7fffu + ((v.u >> 16) & 1u);
  return (short)(r >> 16);
}

// ---------------------------------------------------------------------------
// LayerNorm: fp32 row in -> bf16 row out.  One block per row, 256 threads.
// ---------------------------------------------------------------------------
__global__ __launch_bounds__(256) void ln_kernel(
    const float* __restrict__ x, const float* __restrict__ g,
    const float* __restrict__ be, short* __restrict__ out)
{
  const int row = blockIdx.x;
  const int tid = threadIdx.x;
  const float4 v = ((const float4*)(x + (size_t)row * D_))[tid];
  float s1 = v.x + v.y + v.z + v.w;
  float s2 = v.x*v.x + v.y*v.y + v.z*v.z + v.w*v.w;
#pragma unroll
  for (int off = 1; off < 64; off <<= 1) {
    s1 += __shfl_xor(s1, off);
    s2 += __shfl_xor(s2, off);
  }
  __shared__ float r1[4], r2[4];
  if ((tid & 63) == 0) { r1[tid >> 6] = s1; r2[tid >> 6] = s2; }
  __syncthreads();
  s1 = r1[0] + r1[1] + r1[2] + r1[3];
  s2 = r2[0] + r2[1] + r2[2] + r2[3];
  const float mu = s1 * (1.0f / D_);
  const float var = s2 * (1.0f / D_) - mu * mu;
  const float rs = rsqrtf(var + 1e-5f);
  const float4 gv = ((const float4*)g)[tid];
  const float4 bv = ((const float4*)be)[tid];
  short4v o;
  o.x = f2bf((v.x - mu) * rs * gv.x + bv.x);
  o.y = f2bf((v.y - mu) * rs * gv.y + bv.y);
  o.z = f2bf((v.z - mu) * rs * gv.z + bv.z);
  o.w = f2bf((v.w - mu) * rs * gv.w + bv.w);
  *(short4v*)&out[(size_t)row * D_ + tid * 4] = o;
}

// ---------------------------------------------------------------------------
// Batched weight transpose + cast: all six weights in ONE launch.
// ---------------------------------------------------------------------------
__global__ __launch_bounds__(256) void transpose_all(
    const float* __restrict__ wq, const float* __restrict__ wk,
    const float* __restrict__ wv, const float* __restrict__ wo,
    const float* __restrict__ w1, const float* __restrict__ w2,
    short* __restrict__ wqkvT, short* __restrict__ woT,
    short* __restrict__ w1T, short* __restrict__ w2T)
{
  const uint32_t pid = blockIdx.x;
  const float* in; short* out;
  int R, C, tile, xsh;
  if (pid < 4096) {
    const int which = pid >> 10; tile = pid & 1023;
    R = 1024; C = 1024; xsh = 5;
    in  = (which == 0) ? wq : (which == 1) ? wk : (which == 2) ? wv : wo;
    out = (which == 3) ? woT : wqkvT + (size_t)which * 1024 * 1024;
  } else if (pid < 8192) {
    tile = pid - 4096; R = 1024; C = 4096; xsh = 7; in = w1; out = w1T;
  } else {
    tile = pid - 8192; R = 4096; C = 1024; xsh = 5; in = w2; out = w2T;
  }
  const int c0 = (tile & ((1 << xsh) - 1)) * 32;
  const int r0 = (tile >> xsh) * 32;

  __shared__ float t[32][33];
  const int tx = threadIdx.x & 31, ty = threadIdx.x >> 5;
#pragma unroll
  for (int i = 0; i < 4; i++)
    t[ty + i * 8][tx] = in[(size_t)(r0 + ty + i * 8) * C + c0 + tx];
  __syncthreads();
#pragma unroll
  for (int i = 0; i < 4; i++)
    out[(size_t)(c0 + ty + i * 8) * R + r0 + tx] = f2bf(t[tx][ty + i * 8]);
}

// ---------------------------------------------------------------------------
// bf16 GEMM (128x128): C[M,N] = A[M,K] @ Bt[N,K]^T.  (exact R17/R14 shape)
// ---------------------------------------------------------------------------
__global__ __launch_bounds__(256, 4) void gemm_bt(
    const short* __restrict__ A, const short* __restrict__ Bt,
    float* __restrict__ outf, short* __restrict__ outb,
    short* __restrict__ outbK, short* __restrict__ vtT,
    const float* __restrict__ bias, const float* __restrict__ resid,
    int M, int N, int K, int do_relu, int split, int group)
{
  __shared__ short As[2 * 128 * 32];   // [half][row][32]
  __shared__ short Bs[2 * 128 * 32];
  const int tid = threadIdx.x;
  const int wave = tid >> 6;
  const int lane = tid & 63;
  const int quad = lane >> 4;
  const int l16 = lane & 15;

  const uint32_t nblk = gridDim.x;
  const uint32_t pid = blockIdx.y * nblk + blockIdx.x;
  const uint32_t nig = (uint32_t)group * nblk;
  const uint32_t gid = pid / nig;
  const uint32_t within = pid - gid * nig;
  const uint32_t bm = gid * group + within % group;
  const uint32_t bn = within / group;
  const int tm = bm * 128;
  const int tn = bn * 128;

  const int wm = (wave & 1) * 64;
  const int wn = (wave >> 1) * 64;
  const int srow = lane >> 2;
  const int sgran = ((lane & 3) ^ ((lane >> 3) & 3)) * 8;  // swizzled source granule
  const int rg = (l16 >> 1) & 3;                           // read-side swizzle

  floatx4 acc[4][4];
#pragma unroll
  for (int i = 0; i < 4; i++)
#pragma unroll
    for (int j = 0; j < 4; j++) acc[i][j] = floatx4{0.f, 0.f, 0.f, 0.f};

  const short* gA0 = A + (size_t)(tm + wave * 32 + srow) * K + sgran;
  const short* gB0 = Bt + (size_t)(tn + wave * 32 + srow) * K + sgran;

  for (int kt = 0; kt < K; kt += 64) {
    __syncthreads();
    __builtin_amdgcn_global_load_lds((gas_ptr)(gA0 + kt),                      (las_ptr)(&As[wave * 1024]),        16, 0, 0);
    __builtin_amdgcn_global_load_lds((gas_ptr)(gA0 + kt + (size_t)16 * K),     (las_ptr)(&As[wave * 1024 + 512]),  16, 0, 0);
    __builtin_amdgcn_global_load_lds((gas_ptr)(gB0 + kt),                      (las_ptr)(&Bs[wave * 1024]),        16, 0, 0);
    __builtin_amdgcn_global_load_lds((gas_ptr)(gB0 + kt + (size_t)16 * K),     (las_ptr)(&Bs[wave * 1024 + 512]),  16, 0, 0);
    __builtin_amdgcn_global_load_lds((gas_ptr)(gA0 + kt + 32),                 (las_ptr)(&As[4096 + wave * 1024]),       16, 0, 0);
    __builtin_amdgcn_global_load_lds((gas_ptr)(gA0 + kt + 32 + (size_t)16 * K),(las_ptr)(&As[4096 + wave * 1024 + 512]), 16, 0, 0);
    __builtin_amdgcn_global_load_lds((gas_ptr)(gB0 + kt + 32),                 (las_ptr)(&Bs[4096 + wave * 1024]),       16, 0, 0);
    __builtin_amdgcn_global_load_lds((gas_ptr)(gB0 + kt + 32 + (size_t)16 * K),(las_ptr)(&Bs[4096 + wave * 1024 + 512]), 16, 0, 0);
    __syncthreads();

#pragma unroll
    for (int ksub = 0; ksub < 2; ksub++) {
      const int hb = ksub * 4096;
      short8 af[4], bfv[4];
#pragma unroll
      for (int mi = 0; mi < 4; mi++)
        af[mi] = *(const short8*)&As[hb + (wm + mi * 16 + l16) * 32 + (quad ^ rg) * 8];
#pragma unroll
      for (int ni = 0; ni < 4; ni++)
        bfv[ni] = *(const short8*)&Bs[hb + (wn + ni * 16 + l16) * 32 + (quad ^ rg) * 8];
#pragma unroll
      for (int mi = 0; mi < 4; mi++)
#pragma unroll
        for (int ni = 0; ni < 4; ni++)
          acc[mi][ni] = __builtin_amdgcn_mfma_f32_16x16x32_bf16(af[mi], bfv[ni], acc[mi][ni], 0, 0, 0);
    }
  }

  short* ob = outb;
  int Nst = N;
  int cbase = tn;
  int vpart = 0;
  if (split) {
    const int part = tn >> 10;
    if (part == 2) vpart = 1;
    else ob = (part == 0) ? outb : outbK;
    Nst = D_;
    cbase = tn & (D_ - 1);
  }

  if (vpart) {
#pragma unroll
    for (int mi = 0; mi < 4; mi++) {
      const int row0 = tm + wm + mi * 16 + quad * 4;
      const int bb = row0 >> 11, s0r = row0 & 2047;
#pragma unroll
      for (int ni = 0; ni < 4; ni++) {
        const int cst = cbase + wn + ni * 16 + l16;
        short4v o;
#pragma unroll
        for (int r = 0; r < 4; r++) o[r] = f2bf(acc[mi][ni][r]);
        *(short4v*)&vtT[((size_t)(bb << 10) + cst) * (size_t)S_ + s0r] = o;
      }
    }
    return;
  }

#pragma unroll
  for (int mi = 0; mi < 4; mi++) {
    const int row0 = tm + wm + mi * 16 + quad * 4;
#pragma unroll
    for (int ni = 0; ni < 4; ni++) {
      const int col = tn + wn + ni * 16 + l16;
      const int cst = cbase + wn + ni * 16 + l16;
      const float bv = bias ? bias[col] : 0.0f;
#pragma unroll
      for (int r = 0; r < 4; r++) {
        const size_t idx = (size_t)(row0 + r) * Nst + cst;
        float v = acc[mi][ni][r] + bv;
        if (do_relu) v = fmaxf(v, 0.0f);
        if (resid) v += resid[idx];
        if (outf) outf[idx] = v;
        if (ob) ob[idx] = f2bf(v);
      }
    }
  }
}

// ---------------------------------------------------------------------------
// bf16 GEMM (128x64), exact R17 shape (BK=64, swizzled, 4 blocks/CU).
// R18's BK=128 REGRESSED (103->133: occupancy 4->3 + longer drain). Reverted.
// ---------------------------------------------------------------------------
__global__ __launch_bounds__(256, 4) void gemm_bt_n64(
    const short* __restrict__ A, const short* __restrict__ Bt,
    float* __restrict__ outf,
    const float* __restrict__ bias, const float* __restrict__ resid,
    int M, int N, int K, int group)
{
  __shared__ short As[2 * 128 * 32];
  __shared__ short Bs[2 * 64 * 32];
  const int tid = threadIdx.x;
  const int wave = tid >> 6;
  const int lane = tid & 63;
  const int quad = lane >> 4;
  const int l16 = lane & 15;

  const uint32_t nblk = gridDim.x;
  const uint32_t pid = blockIdx.y * nblk + blockIdx.x;
  const uint32_t nig = (uint32_t)group * nblk;
  const uint32_t gid = pid / nig;
  const uint32_t within = pid - gid * nig;
  const uint32_t bm = gid * group + within % group;
  const uint32_t bn = within / group;
  const int tm = bm * 128;
  const int tn = bn * 64;

  const int wm = (wave & 1) * 64;
  const int wn = (wave >> 1) * 32;
  const int srow = lane >> 2;
  const int sgran = ((lane & 3) ^ ((lane >> 3) & 3)) * 8;  // swizzled source granule
  const int rg = (l16 >> 1) & 3;                           // read-side swizzle

  floatx4 acc[4][2];
#pragma unroll
  for (int i = 0; i < 4; i++)
#pragma unroll
    for (int j = 0; j < 2; j++) acc[i][j] = floatx4{0.f, 0.f, 0.f, 0.f};

  const short* gA0 = A + (size_t)(tm + wave * 32 + srow) * K + sgran;
  const short* gB0 = Bt + (size_t)(tn + wave * 16 + srow) * K + sgran;

  for (int kt = 0; kt < K; kt += 64) {
    __syncthreads();
    __builtin_amdgcn_global_load_lds((gas_ptr)(gA0 + kt),                      (las_ptr)(&As[wave * 1024]),        16, 0, 0);
    __builtin_amdgcn_global_load_lds((gas_ptr)(gA0 + kt + (size_t)16 * K),     (las_ptr)(&As[wave * 1024 + 512]),  16, 0, 0);
    __builtin_amdgcn_global_load_lds((gas_ptr)(gA0 + kt + 32),                 (las_ptr)(&As[4096 + wave * 1024]),       16, 0, 0);
    __builtin_amdgcn_global_load_lds((gas_ptr)(gA0 + kt + 32 + (size_t)16 * K),(las_ptr)(&As[4096 + wave * 1024 + 512]), 16, 0, 0);
    __builtin_amdgcn_global_load_lds((gas_ptr)(gB0 + kt),      (las_ptr)(&Bs[wave * 512]),        16, 0, 0);
    __builtin_amdgcn_global_load_lds((gas_ptr)(gB0 + kt + 32), (las_ptr)(&Bs[2048 + wave * 512]), 16, 0, 0);
    __syncthreads();

#pragma unroll
    for (int ksub = 0; ksub < 2; ksub++) {
      const int ha = ksub * 4096;
      const int hbv = ksub * 2048;
      short8 af[4], bfv[2];
#pragma unroll
      for (int mi = 0; mi < 4; mi++)
        af[mi] = *(const short8*)&As[ha + (wm + mi * 16 + l16) * 32 + (quad ^ rg) * 8];
#pragma unroll
      for (int ni = 0; ni < 2; ni++)
        bfv[ni] = *(const short8*)&Bs[hbv + (wn + ni * 16 + l16) * 32 + (quad ^ rg) * 8];
#pragma unroll
      for (int mi = 0; mi < 4; mi++)
#pragma unroll
        for (int ni = 0; ni < 2; ni++)
          acc[mi][ni] = __builtin_amdgcn_mfma_f32_16x16x32_bf16(af[mi], bfv[ni], acc[mi][ni], 0, 0, 0);
    }
  }

#pragma unroll
  for (int mi = 0; mi < 4; mi++) {
    const int row0 = tm + wm + mi * 16 + quad * 4;
#pragma unroll
    for (int ni = 0; ni < 2; ni++) {
      const int col = tn + wn + ni * 16 + l16;
      const float bv = bias ? bias[col] : 0.0f;
#pragma unroll
      for (int r = 0; r < 4; r++) {
        const size_t idx = (size_t)(row0 + r) * N + col;
        float v = acc[mi][ni][r] + bv;
        if (resid) v += resid[idx];
        outf[idx] = v;
      }
    }
  }
}

// ---------------------------------------------------------------------------
// R19 NEW: 256x256 8-phase GEMM (T3+T4 structure) — bf16 out + bias + relu.
// 512 threads (8 waves 2Mx4N), BK=64, 2 K-tiles/iter, 128 KB LDS (2 bufs x
// (A 32KB + B 32KB)).  Per phase: {vmcnt(0) at phases 0/4 only -> s_barrier
// -> sched_barrier -> 12 ds_read_b128 (one C-quadrant) -> 2 DMA stages ->
// 16 MFMA}.  Safety: tile halves land >=4 phases before first read, published
// by the phase-0/4 vmcnt+barrier; each buffer staged only after the barrier
// following its last read phase (write-after-read).  Granule swizzle:
// LDS[R][g] = SRC[R][g ^ (R&7)] via pre-permuted source; reads at g^(l16&7).
// ---------------------------------------------------------------------------
__global__ __launch_bounds__(512, 2) void gemm256(
    const short* __restrict__ A, const short* __restrict__ Bt,
    short* __restrict__ outb, const float* __restrict__ bias,
    int M, int N, int K, int do_relu, int group)
{
  __shared__ short As[2][256 * 64];   // 64 KB
  __shared__ short Bs[2][256 * 64];   // 64 KB
  const int tid = threadIdx.x;
  const int wave = tid >> 6;
  const int lane = tid & 63;
  const int quad = (lane >> 4) & 3;
  const int l16 = lane & 15;

  // GROUP_M swizzle
  const uint32_t nblk = gridDim.x;
  const uint32_t pid = blockIdx.y * nblk + blockIdx.x;
  const uint32_t nig = (uint32_t)group * nblk;
  const uint32_t gid = pid / nig;
  const uint32_t within = pid - gid * nig;
  const uint32_t bm = gid * group + within % group;
  const uint32_t bn = within / group;
  const int tm = bm * 256;
  const int tn = bn * 256;

  const int wmBase = ((wave >> 2) & 1) * 128;  // this wave's A-half (128 rows)
  const int wnBase = (wave & 3) * 64;          // this wave's B-quarter (64 rows)

  // staging geometry: one issue = wave covers 8 rows x 8 granules (16B each)
  const int srow8 = lane >> 3;                      // row-in-8
  const int sgran = ((lane & 7) ^ srow8) * 8;       // pre-swizzled source granule

  floatx4 acc[8][4];
#pragma unroll
  for (int i = 0; i < 8; i++)
#pragma unroll
    for (int j = 0; j < 4; j++) acc[i][j] = floatx4{0.f, 0.f, 0.f, 0.f};

  const short* gA = A + (size_t)(tm + wave * 8 + srow8) * K + sgran;
  const short* gB = Bt + (size_t)(tn + wave * 8 + srow8) * K + sgran;

  // stage one 64-row slab (matrix half `hf`, slab `is`) of a K-tile
#define ST_A(buf, kt, hf, is) \
  __builtin_amdgcn_global_load_lds((gas_ptr)(gA + (size_t)((hf) * 128 + (is) * 64) * K + (kt)), \
      (las_ptr)(&As[buf][((hf) * 128 + (is) * 64 + wave * 8) * 64]), 16, 0, 0)
#define ST_B(buf, kt, hf, is) \
  __builtin_amdgcn_global_load_lds((gas_ptr)(gB + (size_t)((hf) * 128 + (is) * 64) * K + (kt)), \
      (las_ptr)(&Bs[buf][((hf) * 128 + (is) * 64 + wave * 8) * 64]), 16, 0, 0)

  // prologue: tile 0 -> buf0 (8 issues per wave)
  ST_A(0, 0, 0, 0); ST_A(0, 0, 0, 1); ST_A(0, 0, 1, 0); ST_A(0, 0, 1, 1);
  ST_B(0, 0, 0, 0); ST_B(0, 0, 0, 1); ST_B(0, 0, 1, 0); ST_B(0, 0, 1, 1);

  const int niter = K >> 7;   // 2 K-tiles (128) per iteration; K % 128 == 0
  for (int it = 0; it < niter; ++it) {
    const int kt1 = it * 128 + 64;    // tile 2it+1 -> buf1 (staged phases 0-3)
    const int kt2 = it * 128 + 128;   // tile 2it+2 -> buf0 (staged phases 4-7)
#pragma unroll
    for (int p = 0; p < 8; ++p) {
      if ((p & 3) == 0) asm volatile("s_waitcnt vmcnt(0)" ::: "memory");
      __builtin_amdgcn_s_barrier();
      __builtin_amdgcn_sched_barrier(0);  // pin phase head: no hoist of reads/stages

      const int buf = p >> 2;
      const int mq = (p >> 1) & 1;   // m-half of quadrant
      const int nq = p & 1;          // n-half of quadrant

      // 12 ds_reads for this quadrant
      short8 af[4][2], bf[2][2];
#pragma unroll
      for (int mi = 0; mi < 4; mi++)
#pragma unroll
        for (int ks = 0; ks < 2; ks++)
          af[mi][ks] = *(const short8*)&As[buf][(wmBase + (mq * 4 + mi) * 16 + l16) * 64 +
                                               (((ks * 4 + quad) ^ (l16 & 7)) * 8)];
#pragma unroll
      for (int ni = 0; ni < 2; ni++)
#pragma unroll
        for (int ks = 0; ks < 2; ks++)
          bf[ni][ks] = *(const short8*)&Bs[buf][(wnBase + (nq * 2 + ni) * 16 + l16) * 64 +
                                               (((ks * 4 + quad) ^ (l16 & 7)) * 8)];

      // 2 DMA stages (one 64-row slab)
      if (p < 4) {
        if (p == 0)      { ST_A(1, kt1, 0, 0); ST_A(1, kt1, 0, 1); }
        else if (p == 1) { ST_A(1, kt1, 1, 0); ST_A(1, kt1, 1, 1); }
        else if (p == 2) { ST_B(1, kt1, 0, 0); ST_B(1, kt1, 0, 1); }
        else             { ST_B(1, kt1, 1, 0); ST_B(1, kt1, 1, 1); }
      } else if (kt2 < K) {
        if (p == 4)      { ST_A(0, kt2, 0, 0); ST_A(0, kt2, 0, 1); }
        else if (p == 5) { ST_A(0, kt2, 1, 0); ST_A(0, kt2, 1, 1); }
        else if (p == 6) { ST_B(0, kt2, 0, 0); ST_B(0, kt2, 0, 1); }
        else             { ST_B(0, kt2, 1, 0); ST_B(0, kt2, 1, 1); }
      }

      // 16 MFMA (compiler inserts lgkmcnt for the ds_read deps)
      __builtin_amdgcn_s_setprio(1);
#pragma unroll
      for (int mi = 0; mi < 4; mi++)
#pragma unroll
        for (int ni = 0; ni < 2; ni++)
#pragma unroll
          for (int ks = 0; ks < 2; ks++)
            acc[mq * 4 + mi][nq * 2 + ni] = __builtin_amdgcn_mfma_f32_16x16x32_bf16(
                af[mi][ks], bf[ni][ks], acc[mq * 4 + mi][nq * 2 + ni], 0, 0, 0);
      __builtin_amdgcn_s_setprio(0);
    }
  }
#undef ST_A
#undef ST_B

  // epilogue: bias + relu -> bf16
#pragma unroll
  for (int mi = 0; mi < 8; mi++) {
    const int row0 = tm + wmBase + mi * 16 + quad * 4;
#pragma unroll
    for (int ni = 0; ni < 4; ni++) {
      const int col = tn + wnBase + ni * 16 + l16;
      const float bv = bias ? bias[col] : 0.0f;
#pragma unroll
      for (int r = 0; r < 4; r++) {
        float v = acc[mi][ni][r] + bv;
        if (do_relu) v = fmaxf(v, 0.0f);
        outb[(size_t)(row0 + r) * N + col] = f2bf(v);
      }
    }
  }
}

// ---------------------------------------------------------------------------
// Flash attention, R13 (proven): in-register softmax (swapped QK^T, 32x32x16
// MFMA, cvt_pk + permlane32_swap); K/V via global_load_lds double-buffer,
// DMA post-barrier; source-permuted granule swizzle; setprio on MFMA.
// ---------------------------------------------------------------------------
__device__ __forceinline__ int swz64(int row) {
  return (row & 7) ^ ((row >> 3) & 3);
}
__device__ __forceinline__ int kvidx(int row, int scol) {
  return (row << 6) + (scol ^ (swz64(row) << 3));
}

__global__ __launch_bounds__(256, 4) void attn_kernel(
    const short* __restrict__ qb, const short* __restrict__ kb,
    const short* __restrict__ vtb, short* __restrict__ attb)
{
  __shared__ short Ks[2][64 * 64];
  __shared__ short Vts[2][64 * 64];
  __shared__ float lbuf[4][32];

  const int tid = threadIdx.x;
  const int wave = tid >> 6, lane = tid & 63;
  const int l31 = lane & 31, hi = lane >> 5;
  const int qt = blockIdx.x, bh = blockIdx.y;
  const int b = bh >> 4, h = bh & 15;
  const size_t rowbase = (size_t)b * S_;
  const int hcol = h * 64;

  const int lr = lane >> 3, lg = lane & 7;
  const int sgran = (lg ^ lr ^ wave) * 8;
  const short* ksrc = kb + (rowbase + wave * 8 + lr) * D_ + hcol + sgran;
  const short* vsrc = vtb + ((size_t)bh * 64 + wave * 8 + lr) * S_ + sgran;

  short8 qf[4];
  {
    const short* gq = qb + (rowbase + qt * 128 + wave * 32 + l31) * D_ + hcol + hi * 8;
#pragma unroll
    for (int st = 0; st < 4; st++) {
      short8 t = *(const short8*)(gq + st * 16);
#pragma unroll
      for (int i = 0; i < 8; i++) {
        const float f = __uint_as_float(((uint32_t)(uint16_t)t[i]) << 16) * 0.18033688f;
        t[i] = (short)((__float_as_uint(f) + 0x8000u) >> 16);
      }
      qf[st] = t;
    }
  }

  floatx16 Of[2];
#pragma unroll
  for (int nd = 0; nd < 2; nd++)
#pragma unroll
    for (int i = 0; i < 16; i++) Of[nd][i] = 0.f;
  float lrun0 = 0.f, lrun1 = 0.f;

  __builtin_amdgcn_global_load_lds((gas_ptr)ksrc,                      (las_ptr)(&Ks[0][(wave * 8) * 64]),        16, 0, 0);
  __builtin_amdgcn_global_load_lds((gas_ptr)(ksrc + (size_t)32 * D_),  (las_ptr)(&Ks[0][(32 + wave * 8) * 64]),   16, 0, 0);
  __builtin_amdgcn_global_load_lds((gas_ptr)vsrc,                      (las_ptr)(&Vts[0][(wave * 8) * 64]),       16, 0, 0);
  __builtin_amdgcn_global_load_lds((gas_ptr)(vsrc + (size_t)32 * S_),  (las_ptr)(&Vts[0][(32 + wave * 8) * 64]),  16, 0, 0);

  for (int kt = 0; kt < S_; kt += 64) {
    const int cur = (kt >> 6) & 1;
    __syncthreads();

    if (kt + 64 < S_) {
      const int nxt = cur ^ 1;
      const short* kp = ksrc + (size_t)(kt + 64) * D_;
      const short* vp = vsrc + (kt + 64);
      __builtin_amdgcn_global_load_lds((gas_ptr)kp,                      (las_ptr)(&Ks[nxt][(wave * 8) * 64]),        16, 0, 0);
      __builtin_amdgcn_global_load_lds((gas_ptr)(kp + (size_t)32 * D_),  (las_ptr)(&Ks[nxt][(32 + wave * 8) * 64]),   16, 0, 0);
      __builtin_amdgcn_global_load_lds((gas_ptr)vp,                      (las_ptr)(&Vts[nxt][(wave * 8) * 64]),       16, 0, 0);
      __builtin_amdgcn_global_load_lds((gas_ptr)(vp + (size_t)32 * S_),  (las_ptr)(&Vts[nxt][(32 + wave * 8) * 64]),  16, 0, 0);
    }

#pragma unroll
    for (int sub = 0; sub < 2; sub++) {
      floatx16 s;
#pragma unroll
      for (int i = 0; i < 16; i++) s[i] = 0.f;
      __builtin_amdgcn_s_setprio(1);
#pragma unroll
      for (int st = 0; st < 4; st++) {
        const short8 kf = *(const short8*)&Ks[cur][kvidx(sub * 32 + l31, st * 16 + hi * 8)];
        s = __builtin_amdgcn_mfma_f32_32x32x16_bf16(kf, qf[st], s, 0, 0, 0);
      }
      __builtin_amdgcn_s_setprio(0);
      float p[16];
#pragma unroll
      for (int i = 0; i < 16; i++) {
        p[i] = __builtin_amdgcn_exp2f(s[i]);
        if (i & 1) lrun1 += p[i]; else lrun0 += p[i];
      }
      short8 pf[2];
#pragma unroll
      for (int kw = 0; kw < 2; kw++) {
        const int o = kw * 8;
        uint32_t wa, wb, wc, wd;
        asm("v_cvt_pk_bf16_f32 %0, %1, %2" : "=v"(wa) : "v"(p[o + 0]), "v"(p[o + 1]));
        asm("v_cvt_pk_bf16_f32 %0, %1, %2" : "=v"(wb) : "v"(p[o + 4]), "v"(p[o + 5]));
        asm("v_cvt_pk_bf16_f32 %0, %1, %2" : "=v"(wc) : "v"(p[o + 2]), "v"(p[o + 3]));
        asm("v_cvt_pk_bf16_f32 %0, %1, %2" : "=v"(wd) : "v"(p[o + 6]), "v"(p[o + 7]));
        asm("v_permlane32_swap_b32 %0, %1" : "+v"(wa), "+v"(wb));
        asm("v_permlane32_swap_b32 %0, %1" : "+v"(wc), "+v"(wd));
        union { uint32_t u[4]; short8 s8; } pk;
        pk.u[0] = wa; pk.u[1] = wc; pk.u[2] = wb; pk.u[3] = wd;
        pf[kw] = pk.s8;
      }
      __builtin_amdgcn_s_setprio(1);
#pragma unroll
      for (int kw = 0; kw < 2; kw++)
#pragma unroll
        for (int nd = 0; nd < 2; nd++) {
          const short8 vf = *(const short8*)&Vts[cur][kvidx(nd * 32 + l31, sub * 32 + kw * 16 + hi * 8)];
          Of[nd] = __builtin_amdgcn_mfma_f32_32x32x16_bf16(pf[kw], vf, Of[nd], 0, 0, 0);
        }
      __builtin_amdgcn_s_setprio(0);
    }
  }

  const float lrun = lrun0 + lrun1;
  const float ltot = lrun + __shfl_xor(lrun, 32);
  if (hi == 0) lbuf[wave][l31] = ltot;
  asm volatile("" ::: "memory");
#pragma unroll
  for (int reg = 0; reg < 16; reg++) {
    const int q = (reg & 3) + 4 * hi + 8 * (reg >> 2);
    const float inv = 1.0f / lbuf[wave][q];
    const size_t base = (rowbase + qt * 128 + wave * 32 + q) * D_ + hcol + l31;
    attb[base]      = f2bf(Of[0][reg] * inv);
    attb[base + 32] = f2bf(Of[1][reg] * inv);
  }
}

// ---------------------------------------------------------------------------
extern "C" void kernel_launch(void* const* d_in, const int* in_sizes, int n_in,
                              void* d_out, int out_size, void* d_ws, size_t ws_size,
                              hipStream_t stream) {
  const float* x   = (const float*)d_in[0];
  const float* wq  = (const float*)d_in[1];
  const float* wk  = (const float*)d_in[2];
  const float* wv  = (const float*)d_in[3];
  const float* wo  = (const float*)d_in[4];
  const float* w1  = (const float*)d_in[5];
  const float* b1  = (const float*)d_in[6];
  const float* w2  = (const float*)d_in[7];
  const float* b2  = (const float*)d_in[8];
  const float* g1  = (const float*)d_in[9];
  const float* be1 = (const float*)d_in[10];
  const float* g2  = (const float*)d_in[11];
  const float* be2 = (const float*)d_in[12];
  float* out = (float*)d_out;

  const size_t MROWS = (size_t)B_ * S_;  // 8192
  char* p = (char*)d_ws;
  auto take = [&](size_t bytes) { char* r = p; p += (bytes + 255) & ~(size_t)255; return r; };
  short* hb    = (short*)take(MROWS * D_ * 2);   // LN1 out
  short* h2b   = (short*)take(MROWS * D_ * 2);
  short* qbuf  = (short*)take(MROWS * D_ * 2);
  short* kbuf  = (short*)take(MROWS * D_ * 2);
  short* vtb   = (short*)take(MROWS * D_ * 2);   // V transposed (written by QKV GEMM)
  short* attb  = (short*)take(MROWS * D_ * 2);
  short* ffb   = (short*)take(MROWS * DFF_ * 2);
  short* wqkvT = (short*)take((size_t)3 * D_ * D_ * 2);
  short* woT   = (short*)take((size_t)D_ * D_ * 2);
  short* w1T   = (short*)take((size_t)D_ * DFF_ * 2);
  short* w2T   = (short*)take((size_t)DFF_ * D_ * 2);
  float* x1    = (float*)take(MROWS * D_ * 4);

  transpose_all<<<12288, 256, 0, stream>>>(wq, wk, wv, wo, w1, w2,
                                           wqkvT, woT, w1T, w2T);

  ln_kernel<<<MROWS, 256, 0, stream>>>(x, g1, be1, hb);

  gemm_bt<<<dim3(QSTR / 128, MROWS / 128), 256, 0, stream>>>(
      hb, wqkvT, nullptr, qbuf, kbuf, vtb, nullptr, nullptr, MROWS, QSTR, D_, 0, 1, 8);

  attn_kernel<<<dim3(S_ / 128, B_ * H_), 256, 0, stream>>>(qbuf, kbuf, vtb, attb);

  // AO: 128x128 tiles (R17 config)
  gemm_bt<<<dim3(D_ / 128, MROWS / 128), 256, 0, stream>>>(
      attb, woT, x1, nullptr, nullptr, nullptr, nullptr, x, MROWS, D_, D_, 0, 0, 8);

  ln_kernel<<<MROWS, 256, 0, stream>>>(x1, g2, be2, h2b);

  // FFN1: NEW 256x256 8-phase kernel (512 blocks = 2 full generations)
  gemm256<<<dim3(DFF_ / 256, MROWS / 256), 512, 0, stream>>>(
      h2b, w1T, ffb, b1, (int)MROWS, DFF_, D_, 1, 8);

  // FFN2: n64 BK=64 + swizzle (R17 config, measured 103 us)
  gemm_bt_n64<<<dim3(D_ / 64, MROWS / 128), 256, 0, stream>>>(
      ffb, w2T, out, b2, x1, MROWS, D_, DFF_, 4);

  (void)in_sizes; (void)n_in; (void)out_size; (void)ws_size;
}

// Round 12
// 507.075 us; speedup vs baseline: 1.0929x; 1.0370x over previous
//
#include <hip/hip_runtime.h>
#include <stdint.h>

// Problem dims (fixed by reference)
#define B_ 4
#define S_ 2048
#define D_ 1024
#define H_ 16
#define DFF_ 4096
#define QSTR 3072  // fused QKV output width

typedef __attribute__((ext_vector_type(8))) short short8;
typedef __attribute__((ext_vector_type(4))) short short4v;
typedef __attribute__((ext_vector_type(4))) float floatx4;
typedef __attribute__((ext_vector_type(16))) float floatx16;

typedef const __attribute__((address_space(1))) void* gas_ptr;
typedef __attribute__((address_space(3))) void* las_ptr;

__device__ __forceinline__ short f2bf(float f) {
  union { float f; uint32_t u; } v; v.f = f;
  uint32_t r = v.u + 0x7fffu + ((v.u >> 16) & 1u);
  return (short)(r >> 16);
}

// XCD chunk swizzle (T1, m192/m204): nwg MUST be a multiple of 8.
// Blocks 8k..8k+7 (one per XCD by hw round-robin) get work chunks so each
// XCD processes a CONTIGUOUS range of work-ids -> L2 locality.
__device__ __forceinline__ uint32_t xcd_chunk(uint32_t pid, uint32_t nwg) {
  return (pid & 7) * (nwg >> 3) + (pid >> 3);
}

// ---------------------------------------------------------------------------
// LayerNorm: fp32 row in -> bf16 row out.  One block per row, 256 threads.
// ---------------------------------------------------------------------------
__global__ __launch_bounds__(256) void ln_kernel(
    const float* __restrict__ x, const float* __restrict__ g,
    const float* __restrict__ be, short* __restrict__ out)
{
  const int row = blockIdx.x;
  const int tid = threadIdx.x;
  const float4 v = ((const float4*)(x + (size_t)row * D_))[tid];
  float s1 = v.x + v.y + v.z + v.w;
  float s2 = v.x*v.x + v.y*v.y + v.z*v.z + v.w*v.w;
#pragma unroll
  for (int off = 1; off < 64; off <<= 1) {
    s1 += __shfl_xor(s1, off);
    s2 += __shfl_xor(s2, off);
  }
  __shared__ float r1[4], r2[4];
  if ((tid & 63) == 0) { r1[tid >> 6] = s1; r2[tid >> 6] = s2; }
  __syncthreads();
  s1 = r1[0] + r1[1] + r1[2] + r1[3];
  s2 = r2[0] + r2[1] + r2[2] + r2[3];
  const float mu = s1 * (1.0f / D_);
  const float var = s2 * (1.0f / D_) - mu * mu;
  const float rs = rsqrtf(var + 1e-5f);
  const float4 gv = ((const float4*)g)[tid];
  const float4 bv = ((const float4*)be)[tid];
  short4v o;
  o.x = f2bf((v.x - mu) * rs * gv.x + bv.x);
  o.y = f2bf((v.y - mu) * rs * gv.y + bv.y);
  o.z = f2bf((v.z - mu) * rs * gv.z + bv.z);
  o.w = f2bf((v.w - mu) * rs * gv.w + bv.w);
  *(short4v*)&out[(size_t)row * D_ + tid * 4] = o;
}

// ---------------------------------------------------------------------------
// Batched weight transpose + cast: all six weights in ONE launch.
// ---------------------------------------------------------------------------
__global__ __launch_bounds__(256) void transpose_all(
    const float* __restrict__ wq, const float* __restrict__ wk,
    const float* __restrict__ wv, const float* __restrict__ wo,
    const float* __restrict__ w1, const float* __restrict__ w2,
    short* __restrict__ wqkvT, short* __restrict__ woT,
    short* __restrict__ w1T, short* __restrict__ w2T)
{
  const uint32_t pid = blockIdx.x;
  const float* in; short* out;
  int R, C, tile, xsh;
  if (pid < 4096) {
    const int which = pid >> 10; tile = pid & 1023;
    R = 1024; C = 1024; xsh = 5;
    in  = (which == 0) ? wq : (which == 1) ? wk : (which == 2) ? wv : wo;
    out = (which == 3) ? woT : wqkvT + (size_t)which * 1024 * 1024;
  } else if (pid < 8192) {
    tile = pid - 4096; R = 1024; C = 4096; xsh = 7; in = w1; out = w1T;
  } else {
    tile = pid - 8192; R = 4096; C = 1024; xsh = 5; in = w2; out = w2T;
  }
  const int c0 = (tile & ((1 << xsh) - 1)) * 32;
  const int r0 = (tile >> xsh) * 32;

  __shared__ float t[32][33];
  const int tx = threadIdx.x & 31, ty = threadIdx.x >> 5;
#pragma unroll
  for (int i = 0; i < 4; i++)
    t[ty + i * 8][tx] = in[(size_t)(r0 + ty + i * 8) * C + c0 + tx];
  __syncthreads();
#pragma unroll
  for (int i = 0; i < 4; i++)
    out[(size_t)(c0 + ty + i * 8) * R + r0 + tx] = f2bf(t[tx][ty + i * 8]);
}

// ---------------------------------------------------------------------------
// bf16 GEMM (128x128): C[M,N] = A[M,K] @ Bt[N,K]^T.  (R17 shape + T1 swizzle)
// ---------------------------------------------------------------------------
__global__ __launch_bounds__(256, 4) void gemm_bt(
    const short* __restrict__ A, const short* __restrict__ Bt,
    float* __restrict__ outf, short* __restrict__ outb,
    short* __restrict__ outbK, short* __restrict__ vtT,
    const float* __restrict__ bias, const float* __restrict__ resid,
    int M, int N, int K, int do_relu, int split, int group)
{
  __shared__ short As[2 * 128 * 32];   // [half][row][32]
  __shared__ short Bs[2 * 128 * 32];
  const int tid = threadIdx.x;
  const int wave = tid >> 6;
  const int lane = tid & 63;
  const int quad = lane >> 4;
  const int l16 = lane & 15;

  const uint32_t nblk = gridDim.x;
  const uint32_t nwg = nblk * gridDim.y;
  const uint32_t pid = xcd_chunk(blockIdx.y * nblk + blockIdx.x, nwg);
  const uint32_t nig = (uint32_t)group * nblk;
  const uint32_t gid = pid / nig;
  const uint32_t within = pid - gid * nig;
  const uint32_t bm = gid * group + within % group;
  const uint32_t bn = within / group;
  const int tm = bm * 128;
  const int tn = bn * 128;

  const int wm = (wave & 1) * 64;
  const int wn = (wave >> 1) * 64;
  const int srow = lane >> 2;
  const int sgran = ((lane & 3) ^ ((lane >> 3) & 3)) * 8;  // swizzled source granule
  const int rg = (l16 >> 1) & 3;                           // read-side swizzle

  floatx4 acc[4][4];
#pragma unroll
  for (int i = 0; i < 4; i++)
#pragma unroll
    for (int j = 0; j < 4; j++) acc[i][j] = floatx4{0.f, 0.f, 0.f, 0.f};

  const short* gA0 = A + (size_t)(tm + wave * 32 + srow) * K + sgran;
  const short* gB0 = Bt + (size_t)(tn + wave * 32 + srow) * K + sgran;

  for (int kt = 0; kt < K; kt += 64) {
    __syncthreads();
    __builtin_amdgcn_global_load_lds((gas_ptr)(gA0 + kt),                      (las_ptr)(&As[wave * 1024]),        16, 0, 0);
    __builtin_amdgcn_global_load_lds((gas_ptr)(gA0 + kt + (size_t)16 * K),     (las_ptr)(&As[wave * 1024 + 512]),  16, 0, 0);
    __builtin_amdgcn_global_load_lds((gas_ptr)(gB0 + kt),                      (las_ptr)(&Bs[wave * 1024]),        16, 0, 0);
    __builtin_amdgcn_global_load_lds((gas_ptr)(gB0 + kt + (size_t)16 * K),     (las_ptr)(&Bs[wave * 1024 + 512]),  16, 0, 0);
    __builtin_amdgcn_global_load_lds((gas_ptr)(gA0 + kt + 32),                 (las_ptr)(&As[4096 + wave * 1024]),       16, 0, 0);
    __builtin_amdgcn_global_load_lds((gas_ptr)(gA0 + kt + 32 + (size_t)16 * K),(las_ptr)(&As[4096 + wave * 1024 + 512]), 16, 0, 0);
    __builtin_amdgcn_global_load_lds((gas_ptr)(gB0 + kt + 32),                 (las_ptr)(&Bs[4096 + wave * 1024]),       16, 0, 0);
    __builtin_amdgcn_global_load_lds((gas_ptr)(gB0 + kt + 32 + (size_t)16 * K),(las_ptr)(&Bs[4096 + wave * 1024 + 512]), 16, 0, 0);
    __syncthreads();

#pragma unroll
    for (int ksub = 0; ksub < 2; ksub++) {
      const int hb = ksub * 4096;
      short8 af[4], bfv[4];
#pragma unroll
      for (int mi = 0; mi < 4; mi++)
        af[mi] = *(const short8*)&As[hb + (wm + mi * 16 + l16) * 32 + (quad ^ rg) * 8];
#pragma unroll
      for (int ni = 0; ni < 4; ni++)
        bfv[ni] = *(const short8*)&Bs[hb + (wn + ni * 16 + l16) * 32 + (quad ^ rg) * 8];
#pragma unroll
      for (int mi = 0; mi < 4; mi++)
#pragma unroll
        for (int ni = 0; ni < 4; ni++)
          acc[mi][ni] = __builtin_amdgcn_mfma_f32_16x16x32_bf16(af[mi], bfv[ni], acc[mi][ni], 0, 0, 0);
    }
  }

  short* ob = outb;
  int Nst = N;
  int cbase = tn;
  int vpart = 0;
  if (split) {
    const int part = tn >> 10;
    if (part == 2) vpart = 1;
    else ob = (part == 0) ? outb : outbK;
    Nst = D_;
    cbase = tn & (D_ - 1);
  }

  if (vpart) {
#pragma unroll
    for (int mi = 0; mi < 4; mi++) {
      const int row0 = tm + wm + mi * 16 + quad * 4;
      const int bb = row0 >> 11, s0r = row0 & 2047;
#pragma unroll
      for (int ni = 0; ni < 4; ni++) {
        const int cst = cbase + wn + ni * 16 + l16;
        short4v o;
#pragma unroll
        for (int r = 0; r < 4; r++) o[r] = f2bf(acc[mi][ni][r]);
        *(short4v*)&vtT[((size_t)(bb << 10) + cst) * (size_t)S_ + s0r] = o;
      }
    }
    return;
  }

#pragma unroll
  for (int mi = 0; mi < 4; mi++) {
    const int row0 = tm + wm + mi * 16 + quad * 4;
#pragma unroll
    for (int ni = 0; ni < 4; ni++) {
      const int col = tn + wn + ni * 16 + l16;
      const int cst = cbase + wn + ni * 16 + l16;
      const float bv = bias ? bias[col] : 0.0f;
#pragma unroll
      for (int r = 0; r < 4; r++) {
        const size_t idx = (size_t)(row0 + r) * Nst + cst;
        float v = acc[mi][ni][r] + bv;
        if (do_relu) v = fmaxf(v, 0.0f);
        if (resid) v += resid[idx];
        if (outf) outf[idx] = v;
        if (ob) ob[idx] = f2bf(v);
      }
    }
  }
}

// ---------------------------------------------------------------------------
// bf16 GEMM (128x64), R17 shape (BK=64, swizzled, 4 blocks/CU) + T1 swizzle.
// ---------------------------------------------------------------------------
__global__ __launch_bounds__(256, 4) void gemm_bt_n64(
    const short* __restrict__ A, const short* __restrict__ Bt,
    float* __restrict__ outf,
    const float* __restrict__ bias, const float* __restrict__ resid,
    int M, int N, int K, int group)
{
  __shared__ short As[2 * 128 * 32];
  __shared__ short Bs[2 * 64 * 32];
  const int tid = threadIdx.x;
  const int wave = tid >> 6;
  const int lane = tid & 63;
  const int quad = lane >> 4;
  const int l16 = lane & 15;

  const uint32_t nblk = gridDim.x;
  const uint32_t nwg = nblk * gridDim.y;
  const uint32_t pid = xcd_chunk(blockIdx.y * nblk + blockIdx.x, nwg);
  const uint32_t nig = (uint32_t)group * nblk;
  const uint32_t gid = pid / nig;
  const uint32_t within = pid - gid * nig;
  const uint32_t bm = gid * group + within % group;
  const uint32_t bn = within / group;
  const int tm = bm * 128;
  const int tn = bn * 64;

  const int wm = (wave & 1) * 64;
  const int wn = (wave >> 1) * 32;
  const int srow = lane >> 2;
  const int sgran = ((lane & 3) ^ ((lane >> 3) & 3)) * 8;  // swizzled source granule
  const int rg = (l16 >> 1) & 3;                           // read-side swizzle

  floatx4 acc[4][2];
#pragma unroll
  for (int i = 0; i < 4; i++)
#pragma unroll
    for (int j = 0; j < 2; j++) acc[i][j] = floatx4{0.f, 0.f, 0.f, 0.f};

  const short* gA0 = A + (size_t)(tm + wave * 32 + srow) * K + sgran;
  const short* gB0 = Bt + (size_t)(tn + wave * 16 + srow) * K + sgran;

  for (int kt = 0; kt < K; kt += 64) {
    __syncthreads();
    __builtin_amdgcn_global_load_lds((gas_ptr)(gA0 + kt),                      (las_ptr)(&As[wave * 1024]),        16, 0, 0);
    __builtin_amdgcn_global_load_lds((gas_ptr)(gA0 + kt + (size_t)16 * K),     (las_ptr)(&As[wave * 1024 + 512]),  16, 0, 0);
    __builtin_amdgcn_global_load_lds((gas_ptr)(gA0 + kt + 32),                 (las_ptr)(&As[4096 + wave * 1024]),       16, 0, 0);
    __builtin_amdgcn_global_load_lds((gas_ptr)(gA0 + kt + 32 + (size_t)16 * K),(las_ptr)(&As[4096 + wave * 1024 + 512]), 16, 0, 0);
    __builtin_amdgcn_global_load_lds((gas_ptr)(gB0 + kt),      (las_ptr)(&Bs[wave * 512]),        16, 0, 0);
    __builtin_amdgcn_global_load_lds((gas_ptr)(gB0 + kt + 32), (las_ptr)(&Bs[2048 + wave * 512]), 16, 0, 0);
    __syncthreads();

#pragma unroll
    for (int ksub = 0; ksub < 2; ksub++) {
      const int ha = ksub * 4096;
      const int hbv = ksub * 2048;
      short8 af[4], bfv[2];
#pragma unroll
      for (int mi = 0; mi < 4; mi++)
        af[mi] = *(const short8*)&As[ha + (wm + mi * 16 + l16) * 32 + (quad ^ rg) * 8];
#pragma unroll
      for (int ni = 0; ni < 2; ni++)
        bfv[ni] = *(const short8*)&Bs[hbv + (wn + ni * 16 + l16) * 32 + (quad ^ rg) * 8];
#pragma unroll
      for (int mi = 0; mi < 4; mi++)
#pragma unroll
        for (int ni = 0; ni < 2; ni++)
          acc[mi][ni] = __builtin_amdgcn_mfma_f32_16x16x32_bf16(af[mi], bfv[ni], acc[mi][ni], 0, 0, 0);
    }
  }

#pragma unroll
  for (int mi = 0; mi < 4; mi++) {
    const int row0 = tm + wm + mi * 16 + quad * 4;
#pragma unroll
    for (int ni = 0; ni < 2; ni++) {
      const int col = tn + wn + ni * 16 + l16;
      const float bv = bias ? bias[col] : 0.0f;
#pragma unroll
      for (int r = 0; r < 4; r++) {
        const size_t idx = (size_t)(row0 + r) * N + col;
        float v = acc[mi][ni][r] + bv;
        if (resid) v += resid[idx];
        outf[idx] = v;
      }
    }
  }
}

// ---------------------------------------------------------------------------
// Flash attention, R13 + T1: XCD chunking so all 16 qt-blocks of one bh land
// on ONE XCD -> its 512 KB K/V working set stays L2-resident (8 bh/XCD =
// 4 MB = one XCD L2).  R1 measured FETCH 143 MB vs ~55 ideal (K/V refetch).
// ---------------------------------------------------------------------------
__device__ __forceinline__ int swz64(int row) {
  return (row & 7) ^ ((row >> 3) & 3);
}
__device__ __forceinline__ int kvidx(int row, int scol) {
  return (row << 6) + (scol ^ (swz64(row) << 3));
}

__global__ __launch_bounds__(256, 4) void attn_kernel(
    const short* __restrict__ qb, const short* __restrict__ kb,
    const short* __restrict__ vtb, short* __restrict__ attb)
{
  __shared__ short Ks[2][64 * 64];
  __shared__ short Vts[2][64 * 64];
  __shared__ float lbuf[4][32];

  const int tid = threadIdx.x;
  const int wave = tid >> 6, lane = tid & 63;
  const int l31 = lane & 31, hi = lane >> 5;
  // XCD chunk: nwg = 1024, 128 work-ids per XCD = 8 bh per XCD
  const uint32_t pid = xcd_chunk(blockIdx.y * gridDim.x + blockIdx.x, 1024);
  const int qt = pid & 15, bh = pid >> 4;
  const int b = bh >> 4, h = bh & 15;
  const size_t rowbase = (size_t)b * S_;
  const int hcol = h * 64;

  const int lr = lane >> 3, lg = lane & 7;
  const int sgran = (lg ^ lr ^ wave) * 8;
  const short* ksrc = kb + (rowbase + wave * 8 + lr) * D_ + hcol + sgran;
  const short* vsrc = vtb + ((size_t)bh * 64 + wave * 8 + lr) * S_ + sgran;

  short8 qf[4];
  {
    const short* gq = qb + (rowbase + qt * 128 + wave * 32 + l31) * D_ + hcol + hi * 8;
#pragma unroll
    for (int st = 0; st < 4; st++) {
      short8 t = *(const short8*)(gq + st * 16);
#pragma unroll
      for (int i = 0; i < 8; i++) {
        const float f = __uint_as_float(((uint32_t)(uint16_t)t[i]) << 16) * 0.18033688f;
        t[i] = (short)((__float_as_uint(f) + 0x8000u) >> 16);
      }
      qf[st] = t;
    }
  }

  floatx16 Of[2];
#pragma unroll
  for (int nd = 0; nd < 2; nd++)
#pragma unroll
    for (int i = 0; i < 16; i++) Of[nd][i] = 0.f;
  float lrun0 = 0.f, lrun1 = 0.f;

  __builtin_amdgcn_global_load_lds((gas_ptr)ksrc,                      (las_ptr)(&Ks[0][(wave * 8) * 64]),        16, 0, 0);
  __builtin_amdgcn_global_load_lds((gas_ptr)(ksrc + (size_t)32 * D_),  (las_ptr)(&Ks[0][(32 + wave * 8) * 64]),   16, 0, 0);
  __builtin_amdgcn_global_load_lds((gas_ptr)vsrc,                      (las_ptr)(&Vts[0][(wave * 8) * 64]),       16, 0, 0);
  __builtin_amdgcn_global_load_lds((gas_ptr)(vsrc + (size_t)32 * S_),  (las_ptr)(&Vts[0][(32 + wave * 8) * 64]),  16, 0, 0);

  for (int kt = 0; kt < S_; kt += 64) {
    const int cur = (kt >> 6) & 1;
    __syncthreads();

    if (kt + 64 < S_) {
      const int nxt = cur ^ 1;
      const short* kp = ksrc + (size_t)(kt + 64) * D_;
      const short* vp = vsrc + (kt + 64);
      __builtin_amdgcn_global_load_lds((gas_ptr)kp,                      (las_ptr)(&Ks[nxt][(wave * 8) * 64]),        16, 0, 0);
      __builtin_amdgcn_global_load_lds((gas_ptr)(kp + (size_t)32 * D_),  (las_ptr)(&Ks[nxt][(32 + wave * 8) * 64]),   16, 0, 0);
      __builtin_amdgcn_global_load_lds((gas_ptr)vp,                      (las_ptr)(&Vts[nxt][(wave * 8) * 64]),       16, 0, 0);
      __builtin_amdgcn_global_load_lds((gas_ptr)(vp + (size_t)32 * S_),  (las_ptr)(&Vts[nxt][(32 + wave * 8) * 64]),  16, 0, 0);
    }

#pragma unroll
    for (int sub = 0; sub < 2; sub++) {
      floatx16 s;
#pragma unroll
      for (int i = 0; i < 16; i++) s[i] = 0.f;
      __builtin_amdgcn_s_setprio(1);
#pragma unroll
      for (int st = 0; st < 4; st++) {
        const short8 kf = *(const short8*)&Ks[cur][kvidx(sub * 32 + l31, st * 16 + hi * 8)];
        s = __builtin_amdgcn_mfma_f32_32x32x16_bf16(kf, qf[st], s, 0, 0, 0);
      }
      __builtin_amdgcn_s_setprio(0);
      float p[16];
#pragma unroll
      for (int i = 0; i < 16; i++) {
        p[i] = __builtin_amdgcn_exp2f(s[i]);
        if (i & 1) lrun1 += p[i]; else lrun0 += p[i];
      }
      short8 pf[2];
#pragma unroll
      for (int kw = 0; kw < 2; kw++) {
        const int o = kw * 8;
        uint32_t wa, wb, wc, wd;
        asm("v_cvt_pk_bf16_f32 %0, %1, %2" : "=v"(wa) : "v"(p[o + 0]), "v"(p[o + 1]));
        asm("v_cvt_pk_bf16_f32 %0, %1, %2" : "=v"(wb) : "v"(p[o + 4]), "v"(p[o + 5]));
        asm("v_cvt_pk_bf16_f32 %0, %1, %2" : "=v"(wc) : "v"(p[o + 2]), "v"(p[o + 3]));
        asm("v_cvt_pk_bf16_f32 %0, %1, %2" : "=v"(wd) : "v"(p[o + 6]), "v"(p[o + 7]));
        asm("v_permlane32_swap_b32 %0, %1" : "+v"(wa), "+v"(wb));
        asm("v_permlane32_swap_b32 %0, %1" : "+v"(wc), "+v"(wd));
        union { uint32_t u[4]; short8 s8; } pk;
        pk.u[0] = wa; pk.u[1] = wc; pk.u[2] = wb; pk.u[3] = wd;
        pf[kw] = pk.s8;
      }
      __builtin_amdgcn_s_setprio(1);
#pragma unroll
      for (int kw = 0; kw < 2; kw++)
#pragma unroll
        for (int nd = 0; nd < 2; nd++) {
          const short8 vf = *(const short8*)&Vts[cur][kvidx(nd * 32 + l31, sub * 32 + kw * 16 + hi * 8)];
          Of[nd] = __builtin_amdgcn_mfma_f32_32x32x16_bf16(pf[kw], vf, Of[nd], 0, 0, 0);
        }
      __builtin_amdgcn_s_setprio(0);
    }
  }

  const float lrun = lrun0 + lrun1;
  const float ltot = lrun + __shfl_xor(lrun, 32);
  if (hi == 0) lbuf[wave][l31] = ltot;
  asm volatile("" ::: "memory");
#pragma unroll
  for (int reg = 0; reg < 16; reg++) {
    const int q = (reg & 3) + 4 * hi + 8 * (reg >> 2);
    const float inv = 1.0f / lbuf[wave][q];
    const size_t base = (rowbase + qt * 128 + wave * 32 + q) * D_ + hcol + l31;
    attb[base]      = f2bf(Of[0][reg] * inv);
    attb[base + 32] = f2bf(Of[1][reg] * inv);
  }
}

// ---------------------------------------------------------------------------
extern "C" void kernel_launch(void* const* d_in, const int* in_sizes, int n_in,
                              void* d_out, int out_size, void* d_ws, size_t ws_size,
                              hipStream_t stream) {
  const float* x   = (const float*)d_in[0];
  const float* wq  = (const float*)d_in[1];
  const float* wk  = (const float*)d_in[2];
  const float* wv  = (const float*)d_in[3];
  const float* wo  = (const float*)d_in[4];
  const float* w1  = (const float*)d_in[5];
  const float* b1  = (const float*)d_in[6];
  const float* w2  = (const float*)d_in[7];
  const float* b2  = (const float*)d_in[8];
  const float* g1  = (const float*)d_in[9];
  const float* be1 = (const float*)d_in[10];
  const float* g2  = (const float*)d_in[11];
  const float* be2 = (const float*)d_in[12];
  float* out = (float*)d_out;

  const size_t MROWS = (size_t)B_ * S_;  // 8192
  char* p = (char*)d_ws;
  auto take = [&](size_t bytes) { char* r = p; p += (bytes + 255) & ~(size_t)255; return r; };
  short* hb    = (short*)take(MROWS * D_ * 2);   // LN1 out
  short* h2b   = (short*)take(MROWS * D_ * 2);
  short* qbuf  = (short*)take(MROWS * D_ * 2);
  short* kbuf  = (short*)take(MROWS * D_ * 2);
  short* vtb   = (short*)take(MROWS * D_ * 2);   // V transposed (written by QKV GEMM)
  short* attb  = (short*)take(MROWS * D_ * 2);
  short* ffb   = (short*)take(MROWS * DFF_ * 2);
  short* wqkvT = (short*)take((size_t)3 * D_ * D_ * 2);
  short* woT   = (short*)take((size_t)D_ * D_ * 2);
  short* w1T   = (short*)take((size_t)D_ * DFF_ * 2);
  short* w2T   = (short*)take((size_t)DFF_ * D_ * 2);
  float* x1    = (float*)take(MROWS * D_ * 4);

  transpose_all<<<12288, 256, 0, stream>>>(wq, wk, wv, wo, w1, w2,
                                           wqkvT, woT, w1T, w2T);

  ln_kernel<<<MROWS, 256, 0, stream>>>(x, g1, be1, hb);

  gemm_bt<<<dim3(QSTR / 128, MROWS / 128), 256, 0, stream>>>(
      hb, wqkvT, nullptr, qbuf, kbuf, vtb, nullptr, nullptr, MROWS, QSTR, D_, 0, 1, 8);

  attn_kernel<<<dim3(S_ / 128, B_ * H_), 256, 0, stream>>>(qbuf, kbuf, vtb, attb);

  // AO: 128x128 tiles (R17 config)
  gemm_bt<<<dim3(D_ / 128, MROWS / 128), 256, 0, stream>>>(
      attb, woT, x1, nullptr, nullptr, nullptr, nullptr, x, MROWS, D_, D_, 0, 0, 8);

  ln_kernel<<<MROWS, 256, 0, stream>>>(x1, g2, be2, h2b);

  // FFN1: gemm_bt (R17 config; gemm256 was perf-null, dropped)
  gemm_bt<<<dim3(DFF_ / 128, MROWS / 128), 256, 0, stream>>>(
      h2b, w1T, nullptr, ffb, nullptr, nullptr, b1, nullptr, MROWS, DFF_, D_, 1, 0, 8);

  // FFN2: n64 BK=64 + swizzle (R17 config)
  gemm_bt_n64<<<dim3(D_ / 64, MROWS / 128), 256, 0, stream>>>(
      ffb, w2T, out, b2, x1, MROWS, D_, DFF_, 4);

  (void)in_sizes; (void)n_in; (void)out_size; (void)ws_size;
}